// Round 6
// baseline (233.787 us; speedup 1.0000x reference)
//
#include <hip/hip_runtime.h>
#include <hip/hip_fp16.h>

#define HW 4096
#define NDIM 192
#define CH 16     // scan chunk length (one chunk per front/back block)
#define NC 256    // number of chunks
#define NG 16     // chunk groups (NC/16)

__device__ __forceinline__ int perm_map(int dir, int l) {
  switch (dir & 3) {
    case 0: return l;
    case 1: return 4095 - l;
    case 2: return ((l & 63) << 6) | (l >> 6);
    default: { int m = 4095 - l; return ((m & 63) << 6) | (m >> 6); }
  }
}

__device__ __forceinline__ float siluf(float x) {
  return x * __frcp_rn(1.f + __expf(-x));
}
__device__ __forceinline__ float softplusf(float x) {
  return fmaxf(x, 0.f) + __logf(1.f + __expf(-fabsf(x)));
}

// ---- 1x1 align conv (proven) ----
__global__ void k_align(const float* __restrict__ x, const float* __restrict__ aw,
                        const float* __restrict__ ab, float* __restrict__ xa) {
  __shared__ float law[96][66];
  __shared__ float lxp[64][8];
  int b = blockIdx.y;
  int p0 = blockIdx.x * 8;
  int tid = threadIdx.x + threadIdx.y * 96;
  for (int idx = tid; idx < 96 * 64; idx += 768) {
    int c = idx >> 6, i = idx & 63;
    law[c][i] = aw[c * 64 + i];
  }
  for (int idx = tid; idx < 64 * 8; idx += 768) {
    int i = idx >> 3, pp = idx & 7;
    lxp[i][pp] = x[((size_t)b * 64 + i) * HW + p0 + pp];
  }
  __syncthreads();
  int c = threadIdx.x, pp = threadIdx.y;
  float acc = ab[c];
#pragma unroll 8
  for (int i = 0; i < 64; i++) acc += lxp[i][pp] * law[c][i];
  xa[((size_t)b * HW + p0 + pp) * 96 + c] = acc;
}

// ---- LayerNorm over C=96 (proven) ----
__global__ void k_ln(const float* __restrict__ xa, const float* __restrict__ g,
                     const float* __restrict__ bt, float* __restrict__ xs) {
  int wave = threadIdx.x >> 6, lane = threadIdx.x & 63;
  int p = blockIdx.x * 4 + wave;
  int b = blockIdx.y;
  const float* row = xa + ((size_t)b * HW + p) * 96;
  float v0 = row[lane];
  float v1 = (lane < 32) ? row[64 + lane] : 0.f;
  float s = v0 + v1, s2 = v0 * v0 + v1 * v1;
  for (int o = 32; o; o >>= 1) { s += __shfl_xor(s, o); s2 += __shfl_xor(s2, o); }
  float mu = s * (1.f / 96.f);
  float var = s2 * (1.f / 96.f) - mu * mu;
  float rs = rsqrtf(var + 1e-5f);
  float* orow = xs + ((size_t)b * HW + p) * 96;
  orow[lane] = (v0 - mu) * rs * g[lane] + bt[lane];
  if (lane < 32) orow[64 + lane] = (v1 - mu) * rs * g[64 + lane] + bt[64 + lane];
}

// ---- register-tiled in_proj (proven) ----
__global__ void k_inproj(const float* __restrict__ xs, const float* __restrict__ w,
                         float* __restrict__ x0, float* __restrict__ zs) {
  __shared__ float xt[16][100];
  __shared__ float wt[32][385];
  int b = blockIdx.y;
  int p0 = blockIdx.x * 16;
  int t = threadIdx.x;   // 256
  for (int i = t; i < 16 * 96; i += 256) {
    int pp = i / 96, k = i % 96;
    xt[pp][k] = xs[((size_t)b * HW + p0 + pp) * 96 + k];
  }
  float acc[4][6];
#pragma unroll
  for (int q = 0; q < 4; q++)
#pragma unroll
    for (int j = 0; j < 6; j++) acc[q][j] = 0.f;
  int tx = t & 63, tyq = t >> 6;
  for (int kt = 0; kt < 3; kt++) {
    __syncthreads();
    for (int idx = t; idx < 384 * 32; idx += 256) {
      int o = idx >> 5, k = idx & 31;
      wt[k][o] = w[o * 96 + kt * 32 + k];
    }
    __syncthreads();
#pragma unroll 8
    for (int k = 0; k < 32; k++) {
      float xv[4];
#pragma unroll
      for (int q = 0; q < 4; q++) xv[q] = xt[tyq * 4 + q][kt * 32 + k];
#pragma unroll
      for (int j = 0; j < 6; j++) {
        float wv = wt[k][tx + 64 * j];
#pragma unroll
        for (int q = 0; q < 4; q++) acc[q][j] = fmaf(xv[q], wv, acc[q][j]);
      }
    }
  }
#pragma unroll
  for (int q = 0; q < 4; q++) {
    size_t base = ((size_t)b * HW + p0 + tyq * 4 + q) * NDIM;
#pragma unroll
    for (int j = 0; j < 6; j++) {
      int o = tx + 64 * j;
      if (o < NDIM) x0[base + o] = acc[q][j];
      else          zs[base + (o - NDIM)] = siluf(acc[q][j]);
    }
  }
}

// ---- k_front: conv(regs) + x_proj(k-outer) + dt_proj + local scan ----
// LDS ~14KB, grid 2048 -> 8 blocks/CU
__global__ void k_front(const float* __restrict__ x0,
                        const float* __restrict__ cw, const float* __restrict__ cb,
                        const float* __restrict__ xpw,
                        const float* __restrict__ dtw, const float* __restrict__ dtb,
                        const float* __restrict__ alog,
                        __half2* __restrict__ PS, __half* __restrict__ xd) {
  __shared__ __align__(16) float lu[CH][196];
  __shared__ __half lxh[CH][40];
  int dir = blockIdx.z, b = blockIdx.y, l0 = blockIdx.x * CH;
  int d = threadIdx.x;   // 192
  int bb = dir * 2 + b;
  {
    float cv[CH + 3];
#pragma unroll
    for (int i = 0; i < CH + 3; i++) {
      int l = l0 - 3 + i;
      cv[i] = (l >= 0) ? x0[((size_t)b * HW + perm_map(dir, l)) * NDIM + d] : 0.f;
    }
    float w0 = cw[d * 4], w1 = cw[d * 4 + 1], w2 = cw[d * 4 + 2], w3 = cw[d * 4 + 3];
    float bias = cb[d];
#pragma unroll
    for (int t = 0; t < CH; t++)
      lu[t][d] = siluf(bias + w0 * cv[t] + w1 * cv[t + 1] + w2 * cv[t + 2] + w3 * cv[t + 3]);
  }
  __syncthreads();
  // x_proj: tl = d&15 (row), jg = d>>4 (0..11), j = jg + 12*jj, k-outer
  {
    int tl = d & 15, jg = d >> 4;
    const float4* lur = reinterpret_cast<const float4*>(&lu[tl][0]);
    float acc[4] = {0.f, 0.f, 0.f, 0.f};
#pragma unroll 4
    for (int k = 0; k < 48; k++) {
      float4 a = lur[k];
#pragma unroll
      for (int jj = 0; jj < 4; jj++) {
        int j = jg + 12 * jj;
        if (j < 38) {
          float4 wv = reinterpret_cast<const float4*>(xpw + j * NDIM)[k];
          acc[jj] += a.x * wv.x + a.y * wv.y + a.z * wv.z + a.w * wv.w;
        }
      }
    }
#pragma unroll
    for (int jj = 0; jj < 4; jj++) {
      int j = jg + 12 * jj;
      if (j < 38) {
        __half hv = __float2half_rn(acc[jj]);
        lxh[tl][j] = hv;
        xd[((size_t)bb * HW + l0 + tl) * 40 + j] = hv;
      }
    }
  }
  __syncthreads();
  // dt_proj + softplus
  float del[CH];
  {
    float dw[6];
#pragma unroll
    for (int r = 0; r < 6; r++) dw[r] = dtw[d * 6 + r];
    float db = dtb[d];
#pragma unroll
    for (int t = 0; t < CH; t++) {
      float acc = db;
#pragma unroll
      for (int r = 0; r < 6; r++) acc += dw[r] * __half2float(lxh[t][r]);
      del[t] = softplusf(acc);
    }
  }
  // local scan
  float A[16], h[16], pr[16];
#pragma unroll
  for (int n = 0; n < 16; n++) { A[n] = -__expf(alog[d * 16 + n]); h[n] = 0.f; pr[n] = 1.f; }
#pragma unroll 4
  for (int t = 0; t < CH; t++) {
    float delv = del[t];
    float du = delv * lu[t][d];
#pragma unroll
    for (int n = 0; n < 16; n++) {
      float a = __expf(delv * A[n]);
      h[n] = fmaf(a, h[n], du * __half2float(lxh[t][6 + n]));
      pr[n] *= a;
    }
  }
  size_t ob = (((size_t)bb * NC + blockIdx.x) * 16) * NDIM + d;
#pragma unroll
  for (int n = 0; n < 16; n++)
    PS[ob + (size_t)n * NDIM] = __halves2half2(__float2half_rn(pr[n]), __float2half_rn(h[n]));
}

// ---- B1: in-place exclusive prefix within 16-chunk groups (round-4 proven) ----
__global__ void k_scanB1(__half2* __restrict__ PS,
                         float* __restrict__ Pg, float* __restrict__ Sg) {
  int tid = blockIdx.x * 256 + threadIdx.x;   // 8*16*16*192 = 393216
  int d = tid % NDIM;
  int r = tid / NDIM;
  int n = r & 15; r >>= 4;
  int g = r & 15; r >>= 4;
  int bb = r;               // 0..7
  float Pr = 1.f, Sr = 0.f;
  for (int c = g * 16; c < g * 16 + 16; c++) {
    size_t o = (((size_t)bb * NC + c) * 16 + n) * NDIM + d;
    __half2 v = PS[o];
    float p = __low2float(v), s = __high2float(v);
    PS[o] = __halves2half2(__float2half_rn(Pr), __float2half_rn(Sr));
    Sr = fmaf(p, Sr, s);
    Pr *= p;
  }
  size_t og = (((size_t)bb * NG + g) * 16 + n) * NDIM + d;
  Pg[og] = Pr; Sg[og] = Sr;
}

// ---- B2: serial over 16 groups (round-4 proven) ----
__global__ void k_scanB2(const float* __restrict__ Pg, float* __restrict__ Sg) {
  int tid = blockIdx.x * 256 + threadIdx.x;   // 8*16*192 = 24576
  int d = tid % NDIM;
  int r = tid / NDIM;
  int n = r & 15;
  int bb = r >> 4;          // 0..7
  float h = 0.f;
  for (int g = 0; g < NG; g++) {
    size_t o = (((size_t)bb * NG + g) * 16 + n) * NDIM + d;
    float p = Pg[o], s = Sg[o];
    Sg[o] = h;
    h = fmaf(p, h, s);
  }
}

// ---- k_back: conv(regs) for u; delta/B/C from xd; scan; atomic ysum ----
__global__ void k_back(const float* __restrict__ x0,
                       const float* __restrict__ cw, const float* __restrict__ cb,
                       const __half* __restrict__ xd,
                       const float* __restrict__ dtw, const float* __restrict__ dtb,
                       const float* __restrict__ alog, const float* __restrict__ Dv,
                       const __half2* __restrict__ PS, const float* __restrict__ Sg,
                       const float* __restrict__ zs, float* __restrict__ ysum) {
  __shared__ __half lxh[CH][40];
  int dir = blockIdx.z, b = blockIdx.y, l0 = blockIdx.x * CH;
  int d = threadIdx.x;   // 192
  int bb = dir * 2 + b;
  for (int i = d; i < CH * 38; i += 192) {
    int t = i / 38, j = i % 38;
    lxh[t][j] = xd[((size_t)bb * HW + l0 + t) * 40 + j];
  }
  float uu[CH];
  {
    float cv[CH + 3];
#pragma unroll
    for (int i = 0; i < CH + 3; i++) {
      int l = l0 - 3 + i;
      cv[i] = (l >= 0) ? x0[((size_t)b * HW + perm_map(dir, l)) * NDIM + d] : 0.f;
    }
    float w0 = cw[d * 4], w1 = cw[d * 4 + 1], w2 = cw[d * 4 + 2], w3 = cw[d * 4 + 3];
    float bias = cb[d];
#pragma unroll
    for (int t = 0; t < CH; t++)
      uu[t] = siluf(bias + w0 * cv[t] + w1 * cv[t + 1] + w2 * cv[t + 2] + w3 * cv[t + 3]);
  }
  __syncthreads();
  float A[16], h[16];
  int c = blockIdx.x, g = c >> 4;
#pragma unroll
  for (int n = 0; n < 16; n++) {
    A[n] = -__expf(alog[d * 16 + n]);
    size_t oc = (((size_t)bb * NC + c) * 16 + n) * NDIM + d;
    size_t og = (((size_t)bb * NG + g) * 16 + n) * NDIM + d;
    __half2 v = PS[oc];
    h[n] = fmaf(__low2float(v), Sg[og], __high2float(v));
  }
  float Dd = Dv[d];
  float dw[6];
#pragma unroll
  for (int r = 0; r < 6; r++) dw[r] = dtw[d * 6 + r];
  float db = dtb[d];
#pragma unroll 4
  for (int t = 0; t < CH; t++) {
    float accd = db;
#pragma unroll
    for (int r = 0; r < 6; r++) accd += dw[r] * __half2float(lxh[t][r]);
    float delv = softplusf(accd);
    float du = delv * uu[t];
    float y = 0.f;
#pragma unroll
    for (int n = 0; n < 16; n++) {
      float a = __expf(delv * A[n]);
      h[n] = fmaf(a, h[n], du * __half2float(lxh[t][6 + n]));
      y = fmaf(h[n], __half2float(lxh[t][22 + n]), y);
    }
    y = fmaf(uu[t], Dd, y);
    int p = perm_map(dir, l0 + t);
    size_t po = ((size_t)b * HW + p) * NDIM + d;
    atomicAdd(&ysum[po], 0.25f * y * zs[po]);
  }
}

// ---- k_out: out_proj of summed-gated y + residual ----
__global__ void k_out(const float* __restrict__ ysum, const float* __restrict__ wout,
                      const float* __restrict__ xa, float* __restrict__ out) {
  __shared__ float gb[16][200];
  __shared__ float wt[32][97];
  __shared__ float st[96][18];
  __shared__ float xat[16][97];
  int b = blockIdx.y, p0 = blockIdx.x * 16;
  int t = threadIdx.x;   // 256
  for (int idx = t; idx < 16 * NDIM; idx += 256) {
    int r = idx / NDIM, col = idx % NDIM;
    gb[r][col] = ysum[((size_t)b * HW + p0 + r) * NDIM + col];
  }
  for (int idx = t; idx < 16 * 96; idx += 256) {
    int r = idx / 96, cc = idx % 96;
    xat[r][cc] = xa[((size_t)b * HW + p0 + r) * 96 + cc];
  }
  float acc[2][3];
#pragma unroll
  for (int q = 0; q < 2; q++)
#pragma unroll
    for (int j = 0; j < 3; j++) acc[q][j] = 0.f;
  int tx = t & 31, ty = t >> 5;
  for (int kt = 0; kt < 6; kt++) {
    __syncthreads();
    for (int idx = t; idx < 96 * 32; idx += 256) {
      int o = idx >> 5, k = idx & 31;
      wt[k][o] = wout[o * NDIM + kt * 32 + k];
    }
    __syncthreads();
#pragma unroll 8
    for (int k = 0; k < 32; k++) {
      float xv[2];
#pragma unroll
      for (int q = 0; q < 2; q++) xv[q] = gb[ty * 2 + q][kt * 32 + k];
#pragma unroll
      for (int j = 0; j < 3; j++) {
        float wv = wt[k][tx + 32 * j];
#pragma unroll
        for (int q = 0; q < 2; q++) acc[q][j] = fmaf(xv[q], wv, acc[q][j]);
      }
    }
  }
#pragma unroll
  for (int q = 0; q < 2; q++)
#pragma unroll
    for (int j = 0; j < 3; j++) st[tx + 32 * j][ty * 2 + q] = acc[q][j];
  __syncthreads();
  for (int idx = t; idx < 96 * 16; idx += 256) {
    int cc = idx >> 4, pp = idx & 15;
    out[((size_t)b * 96 + cc) * HW + p0 + pp] = st[cc][pp] + xat[pp][cc];
  }
}

extern "C" void kernel_launch(void* const* d_in, const int* in_sizes, int n_in,
                              void* d_out, int out_size, void* d_ws, size_t ws_size,
                              hipStream_t stream) {
  (void)in_sizes; (void)n_in; (void)out_size; (void)ws_size;
  const float* x    = (const float*)d_in[0];
  const float* aw   = (const float*)d_in[1];
  const float* ab   = (const float*)d_in[2];
  const float* lng  = (const float*)d_in[3];
  const float* lnb  = (const float*)d_in[4];
  const float* ipw  = (const float*)d_in[5];
  const float* cw   = (const float*)d_in[6];
  const float* cb   = (const float*)d_in[7];
  const float* xpw  = (const float*)d_in[8];
  const float* dtw  = (const float*)d_in[9];
  const float* dtb  = (const float*)d_in[10];
  const float* alog = (const float*)d_in[11];
  const float* Dv   = (const float*)d_in[12];
  const float* wout = (const float*)d_in[13];
  float* out = (float*)d_out;
  float* ws = (float*)d_ws;

  float*   xa   = ws;                          // [2][4096][96]        (0)
  float*   x0   = ws + 786432;                 // [2][4096][192]
  float*   zs   = ws + 2359296;                // [2][4096][192]
  float*   xs   = ws + 3932160;                // [2][4096][96] (dead after inproj)
  __half2* PS   = (__half2*)(ws + 3932160);    // [8][256][16][192] half2 (aliases xs)
  float*   Pg   = ws + 10223616;               // [8][16][16][192]
  float*   Sg   = ws + 10616832;               // [8][16][16][192]
  __half*  xd   = (__half*)(ws + 11010048);    // [8][4096][40] half
  float*   ysum = ws + 11665408;               // [2][4096][192]  -> ends 13238272 (53MB)

  hipMemsetAsync(ysum, 0, (size_t)1572864 * sizeof(float), stream);
  k_align<<<dim3(HW / 8, 2), dim3(96, 8), 0, stream>>>(x, aw, ab, xa);
  k_ln<<<dim3(HW / 4, 2), 256, 0, stream>>>(xa, lng, lnb, xs);
  k_inproj<<<dim3(HW / 16, 2), 256, 0, stream>>>(xs, ipw, x0, zs);
  k_front<<<dim3(HW / CH, 2, 4), 192, 0, stream>>>(x0, cw, cb, xpw, dtw, dtb, alog, PS, xd);
  k_scanB1<<<1536, 256, 0, stream>>>(PS, Pg, Sg);
  k_scanB2<<<96, 256, 0, stream>>>(Pg, Sg);
  k_back<<<dim3(HW / CH, 2, 4), 192, 0, stream>>>(x0, cw, cb, xd, dtw, dtb, alog, Dv,
                                                  PS, Sg, zs, ysum);
  k_out<<<dim3(HW / 16, 2), 256, 0, stream>>>(ysum, wout, xa, out);
}